// Round 3
// baseline (89.420 us; speedup 1.0000x reference)
//
#include <hip/hip_runtime.h>
#include <math.h>

namespace {

constexpr int N  = 4096;
constexpr int E  = 256;
constexpr int H  = 8;
constexpr int DH = 32;
constexpr int BS = 8;
// fold 1/sqrt(DH) and log2(e) so softmax runs in exp2 domain
constexpr float CL = 0.17677669529663687f * 1.4426950408889634f;

typedef __bf16 bf16x8 __attribute__((ext_vector_type(8)));
typedef __bf16 bf16x4 __attribute__((ext_vector_type(4)));
typedef __bf16 bf16x2 __attribute__((ext_vector_type(2)));
typedef float  f32x4  __attribute__((ext_vector_type(4)));
typedef unsigned int uint4v __attribute__((ext_vector_type(4)));

#if __has_builtin(__builtin_amdgcn_exp2f)
#define EXP2F(x) __builtin_amdgcn_exp2f(x)
#else
#define EXP2F(x) __expf((x) * 0.6931471805599453f)
#endif

__device__ inline unsigned int pack_bf16x2(float a, float b) {
  bf16x2 t;
  t.x = (__bf16)a;
  t.y = (__bf16)b;
  return __builtin_bit_cast(unsigned int, t);
}

__device__ inline bf16x8 pack8(float4 a, float4 b) {
  bf16x8 r;
  r[0] = (__bf16)a.x; r[1] = (__bf16)a.y; r[2] = (__bf16)a.z; r[3] = (__bf16)a.w;
  r[4] = (__bf16)b.x; r[5] = (__bf16)b.y; r[6] = (__bf16)b.z; r[7] = (__bf16)b.w;
  return r;
}

// ---------------------------------------------------------------------------
// MFMA QKV: out = A @ W^T + b, A = x+pe (Q,K) or x (V), bf16 on-the-fly.
// Block = 64 rows x full E (256) for one matrix. 8 waves: wm in {0,1} picks
// 32-row half, wn in {0..3} picks 64-col slice. Per wave: acc[2 mt][4 nt].
// MFMA mapping (validated by attn round 2): D = mfma(Wfrag, Afrag) ->
//   D row = W's row (n, reg 4g+r), D col = lane&15 = A's row (m).
// Q,K stored bf16 [N][E]; V stored transposed vt[E][N] (scatter bf16 stores).
// Block (x=0, mat=0) also computes batch segment bounds.
// ---------------------------------------------------------------------------
__global__ __launch_bounds__(512) void qkv_mfma(
    const float* __restrict__ x, const float* __restrict__ pe,
    const int* __restrict__ xb,
    const float* __restrict__ Wq, const float* __restrict__ Wk,
    const float* __restrict__ Wv,
    const float* __restrict__ bq, const float* __restrict__ bk,
    const float* __restrict__ bv,
    __bf16* __restrict__ qo, __bf16* __restrict__ ko,
    __bf16* __restrict__ vt, int* __restrict__ seg)
{
  const int mat = blockIdx.y;
  if (mat == 0 && blockIdx.x == 0 && threadIdx.x <= BS) {
    const int t = threadIdx.x;
    int lo = 0, hi = N;
    while (lo < hi) { int mid = (lo + hi) >> 1; if (xb[mid] < t) lo = mid + 1; else hi = mid; }
    seg[t] = lo;
  }
  const int m0   = blockIdx.x * 64;
  const int wave = threadIdx.x >> 6;
  const int wm   = wave >> 2, wn = wave & 3;
  const int lane = threadIdx.x & 63;
  const int l15  = lane & 15, g = lane >> 4;

  const float* __restrict__ W = (mat == 0) ? Wq : (mat == 1 ? Wk : Wv);
  const bool addpe = (mat < 2);
  const int mrow[2] = {m0 + wm * 32 + l15, m0 + wm * 32 + 16 + l15};

  f32x4 acc[2][4];
#pragma unroll
  for (int mt = 0; mt < 2; ++mt)
#pragma unroll
    for (int nt = 0; nt < 4; ++nt) acc[mt][nt] = f32x4{0.f, 0.f, 0.f, 0.f};

  for (int kk = 0; kk < E; kk += 32) {
    bf16x8 af[2];
#pragma unroll
    for (int mt = 0; mt < 2; ++mt) {
      const float* xr = x + (size_t)mrow[mt] * E + kk + 8 * g;
      float4 a0 = *(const float4*)xr;
      float4 a1 = *(const float4*)(xr + 4);
      if (addpe) {
        const float* pr = pe + (size_t)mrow[mt] * E + kk + 8 * g;
        float4 p0 = *(const float4*)pr;
        float4 p1 = *(const float4*)(pr + 4);
        a0.x += p0.x; a0.y += p0.y; a0.z += p0.z; a0.w += p0.w;
        a1.x += p1.x; a1.y += p1.y; a1.z += p1.z; a1.w += p1.w;
      }
      af[mt] = pack8(a0, a1);
    }
    bf16x8 wf[4];
#pragma unroll
    for (int nt = 0; nt < 4; ++nt) {
      const float* wr = W + (size_t)(wn * 64 + nt * 16 + l15) * E + kk + 8 * g;
      wf[nt] = pack8(*(const float4*)wr, *(const float4*)(wr + 4));
    }
#pragma unroll
    for (int mt = 0; mt < 2; ++mt)
#pragma unroll
      for (int nt = 0; nt < 4; ++nt)
        acc[mt][nt] = __builtin_amdgcn_mfma_f32_16x16x32_bf16(wf[nt], af[mt],
                                                              acc[mt][nt], 0, 0, 0);
  }

  if (mat < 2) {
    __bf16* __restrict__ outb = mat ? ko : qo;
    const float* __restrict__ bi = mat ? bk : bq;
#pragma unroll
    for (int mt = 0; mt < 2; ++mt)
#pragma unroll
      for (int nt = 0; nt < 4; ++nt) {
        const int n_base = wn * 64 + nt * 16 + 4 * g;
        const float4 bb = *(const float4*)(bi + n_base);
        bf16x4 o;
        o.x = (__bf16)(acc[mt][nt][0] + bb.x);
        o.y = (__bf16)(acc[mt][nt][1] + bb.y);
        o.z = (__bf16)(acc[mt][nt][2] + bb.z);
        o.w = (__bf16)(acc[mt][nt][3] + bb.w);
        *reinterpret_cast<bf16x4*>(outb + (size_t)mrow[mt] * E + n_base) = o;
      }
  } else {
#pragma unroll
    for (int mt = 0; mt < 2; ++mt)
#pragma unroll
      for (int nt = 0; nt < 4; ++nt) {
        const int n_base = wn * 64 + nt * 16 + 4 * g;
        const float4 bb = *(const float4*)(bv + n_base);
        const float bbr[4] = {bb.x, bb.y, bb.z, bb.w};
#pragma unroll
        for (int r = 0; r < 4; ++r)
          vt[(size_t)(n_base + r) * N + mrow[mt]] = (__bf16)(acc[mt][nt][r] + bbr[r]);
      }
  }
}

// ---------------------------------------------------------------------------
// MFMA flash attention, block-diagonal mask. No LDS, no barriers.
// (unchanged from round 2 except ctx output is bf16)
// ---------------------------------------------------------------------------
__global__ __launch_bounds__(256) void attn_kernel(
    const __bf16* __restrict__ qb, const __bf16* __restrict__ kb,
    const __bf16* __restrict__ vt, const int* __restrict__ xb,
    const int* __restrict__ seg, __bf16* __restrict__ ctxb)
{
  const int h    = blockIdx.y;
  const int wv   = threadIdx.x >> 6;
  const int lane = threadIdx.x & 63;
  const int l15  = lane & 15;
  const int g    = lane >> 4;
  const int hb   = (lane >> 5) & 1;
  const int qrow = blockIdx.x * 64 + wv * 16 + l15;

  const int b  = xb[qrow];
  const int lo = seg[b];
  const int hi = seg[b + 1];

  const bf16x8 qf = *reinterpret_cast<const bf16x8*>(
      qb + (size_t)qrow * E + h * DH + g * 8);

  const int kstart = __shfl(lo, 0, 64);
  const int kend   = __shfl(hi, 15, 64);

  f32x4 acc0 = {0.f, 0.f, 0.f, 0.f};
  f32x4 acc1 = {0.f, 0.f, 0.f, 0.f};
  float m_run = -1.0e30f, l_run = 0.f;

  for (int j0 = kstart & ~63; j0 < kend; j0 += 64) {
    f32x4 s[4];
#pragma unroll
    for (int mt = 0; mt < 4; ++mt) {
      const bf16x8 kf = *reinterpret_cast<const bf16x8*>(
          kb + (size_t)(j0 + 16 * mt + l15) * E + h * DH + g * 8);
      const f32x4 z = {0.f, 0.f, 0.f, 0.f};
      s[mt] = __builtin_amdgcn_mfma_f32_16x16x32_bf16(kf, qf, z, 0, 0, 0);
    }
    bf16x8 vf0[2], vf1[2];
#pragma unroll
    for (int ks = 0; ks < 2; ++ks) {
      vf0[ks] = *reinterpret_cast<const bf16x8*>(
          vt + (size_t)(h * DH + l15) * N + j0 + 32 * ks + 8 * g);
      vf1[ks] = *reinterpret_cast<const bf16x8*>(
          vt + (size_t)(h * DH + 16 + l15) * N + j0 + 32 * ks + 8 * g);
    }

    float p[4][4];
    float tm = -1.0e30f;
#pragma unroll
    for (int mt = 0; mt < 4; ++mt)
#pragma unroll
      for (int r = 0; r < 4; ++r) {
        const int key = j0 + 16 * mt + 4 * g + r;
        float sc = s[mt][r] * CL;
        sc = (key >= lo && key < hi) ? sc : -1.0e30f;
        p[mt][r] = sc;
        tm = fmaxf(tm, sc);
      }
    tm = fmaxf(tm, __shfl_xor(tm, 16, 64));
    tm = fmaxf(tm, __shfl_xor(tm, 32, 64));
    const float mn    = fmaxf(m_run, tm);
    const float alpha = EXP2F(m_run - mn);
    float ts = 0.f;
#pragma unroll
    for (int mt = 0; mt < 4; ++mt)
#pragma unroll
      for (int r = 0; r < 4; ++r) {
        const float sc = p[mt][r];
        const float e  = (sc > -1.0e29f) ? EXP2F(sc - mn) : 0.f;
        p[mt][r] = e;
        ts += e;
      }
    ts += __shfl_xor(ts, 16, 64);
    ts += __shfl_xor(ts, 32, 64);
    m_run = mn;
    l_run = l_run * alpha + ts;
#pragma unroll
    for (int r = 0; r < 4; ++r) { acc0[r] *= alpha; acc1[r] *= alpha; }

    unsigned int pk[4][2];
#pragma unroll
    for (int mt = 0; mt < 4; ++mt) {
      pk[mt][0] = pack_bf16x2(p[mt][0], p[mt][1]);
      pk[mt][1] = pack_bf16x2(p[mt][2], p[mt][3]);
    }
#pragma unroll
    for (int ks = 0; ks < 2; ++ks) {
      unsigned int bwa[4];
#pragma unroll
      for (int w4 = 0; w4 < 4; ++w4) {
        const int gs  = (2 * g + (w4 >> 1)) & 3;
        const int src = (gs << 4) | l15;
        const unsigned int v0 = __shfl(pk[2 * ks][w4 & 1], src, 64);
        const unsigned int v1 = __shfl(pk[2 * ks + 1][w4 & 1], src, 64);
        bwa[w4] = hb ? v1 : v0;
      }
      uint4v bw = {bwa[0], bwa[1], bwa[2], bwa[3]};
      const bf16x8 pf = __builtin_bit_cast(bf16x8, bw);
      acc0 = __builtin_amdgcn_mfma_f32_16x16x32_bf16(vf0[ks], pf, acc0, 0, 0, 0);
      acc1 = __builtin_amdgcn_mfma_f32_16x16x32_bf16(vf1[ks], pf, acc1, 0, 0, 0);
    }
  }

  const float inv = 1.0f / l_run;
  __bf16* orow = ctxb + (size_t)qrow * E + h * DH;
  bf16x4 o0, o1;
  o0.x = (__bf16)(acc0[0] * inv); o0.y = (__bf16)(acc0[1] * inv);
  o0.z = (__bf16)(acc0[2] * inv); o0.w = (__bf16)(acc0[3] * inv);
  o1.x = (__bf16)(acc1[0] * inv); o1.y = (__bf16)(acc1[1] * inv);
  o1.z = (__bf16)(acc1[2] * inv); o1.w = (__bf16)(acc1[3] * inv);
  *reinterpret_cast<bf16x4*>(orow + 4 * g)      = o0;
  *reinterpret_cast<bf16x4*>(orow + 16 + 4 * g) = o1;
}

// ---------------------------------------------------------------------------
// MFMA output projection + residual + LayerNorm, fused.
// Block = 64 rows x full E. Same wave layout as qkv_mfma. After the GEMM,
// y = D + bo + x; row stats via xor16/32 shuffle + cross-wave LDS reduce;
// normalized f32 output written directly.
// ---------------------------------------------------------------------------
__global__ __launch_bounds__(512) void proj_ln(
    const __bf16* __restrict__ ctx, const float* __restrict__ x,
    const float* __restrict__ Wo, const float* __restrict__ bo,
    const float* __restrict__ gamma, const float* __restrict__ beta,
    float* __restrict__ out)
{
  const int m0   = blockIdx.x * 64;
  const int wave = threadIdx.x >> 6;
  const int wm   = wave >> 2, wn = wave & 3;
  const int lane = threadIdx.x & 63;
  const int l15  = lane & 15, g = lane >> 4;
  const int mrow[2] = {m0 + wm * 32 + l15, m0 + wm * 32 + 16 + l15};

  f32x4 acc[2][4];
#pragma unroll
  for (int mt = 0; mt < 2; ++mt)
#pragma unroll
    for (int nt = 0; nt < 4; ++nt) acc[mt][nt] = f32x4{0.f, 0.f, 0.f, 0.f};

  for (int kk = 0; kk < E; kk += 32) {
    bf16x8 af[2];
#pragma unroll
    for (int mt = 0; mt < 2; ++mt)
      af[mt] = *reinterpret_cast<const bf16x8*>(ctx + (size_t)mrow[mt] * E + kk + 8 * g);
    bf16x8 wf[4];
#pragma unroll
    for (int nt = 0; nt < 4; ++nt) {
      const float* wr = Wo + (size_t)(wn * 64 + nt * 16 + l15) * E + kk + 8 * g;
      wf[nt] = pack8(*(const float4*)wr, *(const float4*)(wr + 4));
    }
#pragma unroll
    for (int mt = 0; mt < 2; ++mt)
#pragma unroll
      for (int nt = 0; nt < 4; ++nt)
        acc[mt][nt] = __builtin_amdgcn_mfma_f32_16x16x32_bf16(wf[nt], af[mt],
                                                              acc[mt][nt], 0, 0, 0);
  }

  // y = D + bo + x; per-row partial stats
  float yv[2][4][4];
  float s1[2] = {0.f, 0.f}, s2[2] = {0.f, 0.f};
#pragma unroll
  for (int mt = 0; mt < 2; ++mt)
#pragma unroll
    for (int nt = 0; nt < 4; ++nt) {
      const int n_base = wn * 64 + nt * 16 + 4 * g;
      const float4 bb = *(const float4*)(bo + n_base);
      const float4 xr = *(const float4*)(x + (size_t)mrow[mt] * E + n_base);
      const float bbr[4] = {bb.x, bb.y, bb.z, bb.w};
      const float xrr[4] = {xr.x, xr.y, xr.z, xr.w};
#pragma unroll
      for (int r = 0; r < 4; ++r) {
        const float y = acc[mt][nt][r] + bbr[r] + xrr[r];
        yv[mt][nt][r] = y;
        s1[mt] += y;
        s2[mt] += y * y;
      }
    }
#pragma unroll
  for (int mt = 0; mt < 2; ++mt) {
    s1[mt] += __shfl_xor(s1[mt], 16, 64);
    s2[mt] += __shfl_xor(s2[mt], 16, 64);
    s1[mt] += __shfl_xor(s1[mt], 32, 64);
    s2[mt] += __shfl_xor(s2[mt], 32, 64);
  }

  __shared__ float redS[2][4][2][16];
  __shared__ float redQ[2][4][2][16];
  if (lane < 16) {
    redS[wm][wn][0][l15] = s1[0];
    redS[wm][wn][1][l15] = s1[1];
    redQ[wm][wn][0][l15] = s2[0];
    redQ[wm][wn][1][l15] = s2[1];
  }
  __syncthreads();

  float mu[2], rs[2];
#pragma unroll
  for (int mt = 0; mt < 2; ++mt) {
    float ts = 0.f, tq = 0.f;
#pragma unroll
    for (int w4 = 0; w4 < 4; ++w4) {
      ts += redS[wm][w4][mt][l15];
      tq += redQ[wm][w4][mt][l15];
    }
    mu[mt] = ts * (1.0f / E);
    const float var = tq * (1.0f / E) - mu[mt] * mu[mt];
    rs[mt] = rsqrtf(var + 1e-5f);
  }

#pragma unroll
  for (int mt = 0; mt < 2; ++mt)
#pragma unroll
    for (int nt = 0; nt < 4; ++nt) {
      const int n_base = wn * 64 + nt * 16 + 4 * g;
      const float4 gg = *(const float4*)(gamma + n_base);
      const float4 bt = *(const float4*)(beta + n_base);
      const float ggr[4] = {gg.x, gg.y, gg.z, gg.w};
      const float btr[4] = {bt.x, bt.y, bt.z, bt.w};
      float4 o;
      o.x = (yv[mt][nt][0] - mu[mt]) * rs[mt] * ggr[0] + btr[0];
      o.y = (yv[mt][nt][1] - mu[mt]) * rs[mt] * ggr[1] + btr[1];
      o.z = (yv[mt][nt][2] - mu[mt]) * rs[mt] * ggr[2] + btr[2];
      o.w = (yv[mt][nt][3] - mu[mt]) * rs[mt] * ggr[3] + btr[3];
      *(float4*)(out + (size_t)mrow[mt] * E + n_base) = o;
    }
}

}  // namespace

extern "C" void kernel_launch(void* const* d_in, const int* in_sizes, int n_in,
                              void* d_out, int out_size, void* d_ws, size_t ws_size,
                              hipStream_t stream) {
  const float* x     = (const float*)d_in[0];
  const float* pe    = (const float*)d_in[1];
  const int*   xb    = (const int*)d_in[2];
  const float* Wq    = (const float*)d_in[3];
  const float* Wk    = (const float*)d_in[4];
  const float* Wv    = (const float*)d_in[5];
  const float* bq    = (const float*)d_in[6];
  const float* bk    = (const float*)d_in[7];
  const float* bv    = (const float*)d_in[8];
  const float* Wo    = (const float*)d_in[9];
  const float* bo    = (const float*)d_in[10];
  const float* gamma = (const float*)d_in[11];
  const float* beta  = (const float*)d_in[12];
  float* out = (float*)d_out;

  char* wsb = (char*)d_ws;
  const size_t NE = (size_t)N * E;
  __bf16* qb16  = (__bf16*)(wsb);                  // 2 MB
  __bf16* kb16  = (__bf16*)(wsb + 2 * NE);         // 2 MB
  __bf16* vt16  = (__bf16*)(wsb + 4 * NE);         // 2 MB  [E][N]
  __bf16* ctx16 = (__bf16*)(wsb + 6 * NE);         // 2 MB
  int*    seg   = (int*)(wsb + 8 * NE);

  qkv_mfma<<<dim3(64, 3), 512, 0, stream>>>(x, pe, xb, Wq, Wk, Wv,
                                            bq, bk, bv, qb16, kb16, vt16, seg);
  attn_kernel<<<dim3(64, 8), 256, 0, stream>>>(qb16, kb16, vt16, xb, seg, ctx16);
  proj_ln<<<dim3(64), 512, 0, stream>>>(ctx16, x, Wo, bo, gamma, beta, out);
}

// Round 4
// 83.932 us; speedup vs baseline: 1.0654x; 1.0654x over previous
//
#include <hip/hip_runtime.h>
#include <math.h>

namespace {

constexpr int N  = 4096;
constexpr int E  = 256;
constexpr int H  = 8;
constexpr int DH = 32;
constexpr int BS = 8;
// fold 1/sqrt(DH) and log2(e): softmax in exp2 domain, no max subtraction
// (f32-safe: |s*CL| realistic max ~16, overflow at 127 -> 27 sigma margin)
constexpr float CL = 0.17677669529663687f * 1.4426950408889634f;

typedef __bf16 bf16x8 __attribute__((ext_vector_type(8)));
typedef __bf16 bf16x4 __attribute__((ext_vector_type(4)));
typedef float  f32x4  __attribute__((ext_vector_type(4)));

#if __has_builtin(__builtin_amdgcn_exp2f)
#define EXP2F(x) __builtin_amdgcn_exp2f(x)
#else
#define EXP2F(x) __expf((x) * 0.6931471805599453f)
#endif

__device__ inline bf16x8 pack8(float4 a, float4 b) {
  bf16x8 r;
  r[0] = (__bf16)a.x; r[1] = (__bf16)a.y; r[2] = (__bf16)a.z; r[3] = (__bf16)a.w;
  r[4] = (__bf16)b.x; r[5] = (__bf16)b.y; r[6] = (__bf16)b.z; r[7] = (__bf16)b.w;
  return r;
}

// ---------------------------------------------------------------------------
// MFMA QKV: out = A @ W^T + b, A = x+pe (Q,K) or x (V), bf16 on-the-fly.
// 32-row blocks, grid (128, 3) = 384 blocks (fills 256 CUs).
// 8 waves: wm = wave&1 (16-row half), wn = wave>>1 (64-col slice), acc[4 nt].
// Q,K stored bf16 [N][E]; V stored transposed vt[E][N].
// ---------------------------------------------------------------------------
__global__ __launch_bounds__(512) void qkv_mfma(
    const float* __restrict__ x, const float* __restrict__ pe,
    const int* __restrict__ xb,
    const float* __restrict__ Wq, const float* __restrict__ Wk,
    const float* __restrict__ Wv,
    const float* __restrict__ bq, const float* __restrict__ bk,
    const float* __restrict__ bv,
    __bf16* __restrict__ qo, __bf16* __restrict__ ko,
    __bf16* __restrict__ vt, int* __restrict__ seg)
{
  const int mat = blockIdx.y;
  if (mat == 0 && blockIdx.x == 0 && threadIdx.x <= BS) {
    const int t = threadIdx.x;
    int lo = 0, hi = N;
    while (lo < hi) { int mid = (lo + hi) >> 1; if (xb[mid] < t) lo = mid + 1; else hi = mid; }
    seg[t] = lo;
  }
  const int m0   = blockIdx.x * 32;
  const int wave = threadIdx.x >> 6;
  const int wm   = wave & 1, wn = wave >> 1;
  const int lane = threadIdx.x & 63;
  const int l15  = lane & 15, g = lane >> 4;

  const float* __restrict__ W = (mat == 0) ? Wq : (mat == 1 ? Wk : Wv);
  const bool addpe = (mat < 2);
  const int mrow = m0 + wm * 16 + l15;

  f32x4 acc[4];
#pragma unroll
  for (int nt = 0; nt < 4; ++nt) acc[nt] = f32x4{0.f, 0.f, 0.f, 0.f};

  const float* xr0 = x  + (size_t)mrow * E + 8 * g;
  const float* pr0 = pe + (size_t)mrow * E + 8 * g;

  for (int kk = 0; kk < E; kk += 32) {
    float4 a0 = *(const float4*)(xr0 + kk);
    float4 a1 = *(const float4*)(xr0 + kk + 4);
    if (addpe) {
      float4 p0 = *(const float4*)(pr0 + kk);
      float4 p1 = *(const float4*)(pr0 + kk + 4);
      a0.x += p0.x; a0.y += p0.y; a0.z += p0.z; a0.w += p0.w;
      a1.x += p1.x; a1.y += p1.y; a1.z += p1.z; a1.w += p1.w;
    }
    const bf16x8 af = pack8(a0, a1);
    bf16x8 wf[4];
#pragma unroll
    for (int nt = 0; nt < 4; ++nt) {
      const float* wr = W + (size_t)(wn * 64 + nt * 16 + l15) * E + kk + 8 * g;
      wf[nt] = pack8(*(const float4*)wr, *(const float4*)(wr + 4));
    }
#pragma unroll
    for (int nt = 0; nt < 4; ++nt)
      acc[nt] = __builtin_amdgcn_mfma_f32_16x16x32_bf16(wf[nt], af, acc[nt], 0, 0, 0);
  }

  if (mat < 2) {
    __bf16* __restrict__ outb = mat ? ko : qo;
    const float* __restrict__ bi = mat ? bk : bq;
#pragma unroll
    for (int nt = 0; nt < 4; ++nt) {
      const int n_base = wn * 64 + nt * 16 + 4 * g;
      const float4 bb = *(const float4*)(bi + n_base);
      bf16x4 o;
      o.x = (__bf16)(acc[nt][0] + bb.x);
      o.y = (__bf16)(acc[nt][1] + bb.y);
      o.z = (__bf16)(acc[nt][2] + bb.z);
      o.w = (__bf16)(acc[nt][3] + bb.w);
      *reinterpret_cast<bf16x4*>(outb + (size_t)mrow * E + n_base) = o;
    }
  } else {
#pragma unroll
    for (int nt = 0; nt < 4; ++nt) {
      const int n_base = wn * 64 + nt * 16 + 4 * g;
      const float4 bb = *(const float4*)(bv + n_base);
      const float bbr[4] = {bb.x, bb.y, bb.z, bb.w};
#pragma unroll
      for (int r = 0; r < 4; ++r)
        vt[(size_t)(n_base + r) * N + mrow] = (__bf16)(acc[nt][r] + bbr[r]);
    }
  }
}

// ---------------------------------------------------------------------------
// MFMA flash attention, block-diagonal mask. No LDS, no barriers, and
// (new) ZERO per-tile cross-lane ops:
//  - permuted key IDs: keyid(mt,m)=32(mt>>1)+8(m>>2)+4(mt&1)+(m&3) makes the
//    S^T accumulator registers land exactly in the P A-fragment slots
//  - PV = mfma(P, V-B-frag): ctx rows at reg 4g+r, dims at lane l15
//  - fixed-base exp2 softmax (no running max / rescale; f32-safe by range)
// Cross-lane only at wave end: 2 shfl_xor (l reduce) + 4 shfl (inv bcast).
// ---------------------------------------------------------------------------
__global__ __launch_bounds__(256) void attn_kernel(
    const __bf16* __restrict__ qb, const __bf16* __restrict__ kb,
    const __bf16* __restrict__ vt, const int* __restrict__ xb,
    const int* __restrict__ seg, __bf16* __restrict__ ctxb)
{
  const int h    = blockIdx.y;
  const int wv   = threadIdx.x >> 6;
  const int lane = threadIdx.x & 63;
  const int l15  = lane & 15;
  const int g    = lane >> 4;
  const int hd   = h * DH;
  const int rowbase = blockIdx.x * 64 + wv * 16;
  const int qrow = rowbase + l15;

  const int b  = xb[qrow];
  const int lo = seg[b];
  const int hi = seg[b + 1];

  // Q^T B-fragment: B[k=8g+i][n=l15] = Q[qrow][hd + 8g + i]
  const bf16x8 qf = *reinterpret_cast<const bf16x8*>(
      qb + (size_t)qrow * E + hd + g * 8);

  const int kstart = __shfl(lo, 0, 64);
  const int kend   = __shfl(hi, 15, 64);

  // keyid row offset for the A-fragment load (m = l15)
  const int base_l = ((l15 & 12) << 1) + (l15 & 3);  // 8*(l15>>2) + (l15&3)

  f32x4 acc0 = {0.f, 0.f, 0.f, 0.f};   // ctx[rowbase+4g+r][hd + l15]
  f32x4 acc1 = {0.f, 0.f, 0.f, 0.f};   // ctx[rowbase+4g+r][hd + 16 + l15]
  float lsum = 0.f;                    // sum of P for row l15

  for (int j0 = kstart & ~63; j0 < kend; j0 += 64) {
    // K A-fragments, permuted rows: kf[mt] row = j0 + base_l + 32(mt>>1) + 4(mt&1)
    bf16x8 kf[4];
#pragma unroll
    for (int mt = 0; mt < 4; ++mt) {
      const int krow = j0 + base_l + 32 * (mt >> 1) + 4 * (mt & 1);
      kf[mt] = *reinterpret_cast<const bf16x8*>(kb + (size_t)krow * E + hd + g * 8);
    }
    // V B-fragments: B[k=8g+i][n=l15] = V[j0+32ks+8g+i][hd+16dh+l15] via vt
    bf16x8 vf[2][2];
#pragma unroll
    for (int ks = 0; ks < 2; ++ks)
#pragma unroll
      for (int dh = 0; dh < 2; ++dh)
        vf[ks][dh] = *reinterpret_cast<const bf16x8*>(
            vt + (size_t)(hd + 16 * dh + l15) * N + j0 + 32 * ks + 8 * g);

    // QK^T: s[mt] reg r = S[key j0+32(mt>>1)+8g+4(mt&1)+r][query l15]
    f32x4 s[4];
#pragma unroll
    for (int mt = 0; mt < 4; ++mt) {
      const f32x4 z = {0.f, 0.f, 0.f, 0.f};
      s[mt] = __builtin_amdgcn_mfma_f32_16x16x32_bf16(kf[mt], qf, z, 0, 0, 0);
    }

    // softmax numerators (fixed base), directly into P A-fragment slots
    bf16x8 pa[2];
#pragma unroll
    for (int ks = 0; ks < 2; ++ks)
#pragma unroll
      for (int b_ = 0; b_ < 2; ++b_)
#pragma unroll
        for (int r = 0; r < 4; ++r) {
          const int key = j0 + 32 * ks + 8 * g + 4 * b_ + r;
          const float sc = s[2 * ks + b_][r] * CL;
          const float e  = (key >= lo && key < hi) ? EXP2F(sc) : 0.f;
          lsum += e;
          pa[ks][4 * b_ + r] = (__bf16)e;
        }

    // PV: A = P (in-lane), B = V fragment
#pragma unroll
    for (int ks = 0; ks < 2; ++ks) {
      acc0 = __builtin_amdgcn_mfma_f32_16x16x32_bf16(pa[ks], vf[ks][0], acc0, 0, 0, 0);
      acc1 = __builtin_amdgcn_mfma_f32_16x16x32_bf16(pa[ks], vf[ks][1], acc1, 0, 0, 0);
    }
  }

  // l reduce across the 4 lanes sharing row l15, then broadcast inv to
  // the lanes holding that row's ctx (rows 4g+r live at reg r)
  lsum += __shfl_xor(lsum, 16, 64);
  lsum += __shfl_xor(lsum, 32, 64);
  const float inv = 1.0f / lsum;
  float invr[4];
#pragma unroll
  for (int r = 0; r < 4; ++r) invr[r] = __shfl(inv, 4 * g + r, 64);

  __bf16* __restrict__ cb = ctxb + (size_t)rowbase * E + hd + l15;
#pragma unroll
  for (int r = 0; r < 4; ++r) {
    cb[(size_t)(4 * g + r) * E]      = (__bf16)(acc0[r] * invr[r]);
    cb[(size_t)(4 * g + r) * E + 16] = (__bf16)(acc1[r] * invr[r]);
  }
}

// ---------------------------------------------------------------------------
// MFMA output projection + residual + LayerNorm, fused.
// 16-row blocks, grid 256. 8 waves, wave = wn = 32-col slice, acc[2 nt].
// Orientation: D = mfma(ctx_frag, Wo_frag) -> row = 4g+r (query), col = l15
// so LN output stores are 64B row-contiguous.
// ---------------------------------------------------------------------------
__global__ __launch_bounds__(512) void proj_ln(
    const __bf16* __restrict__ ctx, const float* __restrict__ x,
    const float* __restrict__ Wo, const float* __restrict__ bo,
    const float* __restrict__ gamma, const float* __restrict__ beta,
    float* __restrict__ out)
{
  const int m0   = blockIdx.x * 16;
  const int wn   = threadIdx.x >> 6;
  const int lane = threadIdx.x & 63;
  const int l15  = lane & 15, g = lane >> 4;

  f32x4 acc[2];
  acc[0] = f32x4{0.f, 0.f, 0.f, 0.f};
  acc[1] = f32x4{0.f, 0.f, 0.f, 0.f};

  for (int kk = 0; kk < E; kk += 32) {
    // A-frag: A[m=l15][k=8g+i] = ctx[m0+l15][kk+8g+i]
    const bf16x8 af = *reinterpret_cast<const bf16x8*>(
        ctx + (size_t)(m0 + l15) * E + kk + 8 * g);
    bf16x8 wf[2];
#pragma unroll
    for (int nt = 0; nt < 2; ++nt) {
      const float* wr = Wo + (size_t)(wn * 32 + nt * 16 + l15) * E + kk + 8 * g;
      wf[nt] = pack8(*(const float4*)wr, *(const float4*)(wr + 4));
    }
#pragma unroll
    for (int nt = 0; nt < 2; ++nt)
      acc[nt] = __builtin_amdgcn_mfma_f32_16x16x32_bf16(af, wf[nt], acc[nt], 0, 0, 0);
  }

  // y[m0+4g+r][wn*32+nt*16+l15] = acc[nt][r] + bo + x ; row stats
  float yv[2][4];
  float s1[4], s2[4];
#pragma unroll
  for (int r = 0; r < 4; ++r) { s1[r] = 0.f; s2[r] = 0.f; }
#pragma unroll
  for (int nt = 0; nt < 2; ++nt) {
    const int c = wn * 32 + nt * 16 + l15;
    const float bb = bo[c];
#pragma unroll
    for (int r = 0; r < 4; ++r) {
      const int row = m0 + 4 * g + r;
      const float y = acc[nt][r] + bb + x[(size_t)row * E + c];
      yv[nt][r] = y;
      s1[r] += y;
      s2[r] += y * y;
    }
  }
  // reduce across the 16 l15-lanes (cols within this wave's 32-col slice)
#pragma unroll
  for (int off = 1; off < 16; off <<= 1) {
#pragma unroll
    for (int r = 0; r < 4; ++r) {
      s1[r] += __shfl_xor(s1[r], off, 64);
      s2[r] += __shfl_xor(s2[r], off, 64);
    }
  }
  // cross-wave reduce (8 waves x 16 rows)
  __shared__ float redS[8][16];
  __shared__ float redQ[8][16];
  if (l15 == 0) {
#pragma unroll
    for (int r = 0; r < 4; ++r) {
      redS[wn][4 * g + r] = s1[r];
      redQ[wn][4 * g + r] = s2[r];
    }
  }
  __syncthreads();
  float mu[4], rs[4];
#pragma unroll
  for (int r = 0; r < 4; ++r) {
    float ts = 0.f, tq = 0.f;
#pragma unroll
    for (int w = 0; w < 8; ++w) { ts += redS[w][4 * g + r]; tq += redQ[w][4 * g + r]; }
    mu[r] = ts * (1.0f / E);
    const float var = tq * (1.0f / E) - mu[r] * mu[r];
    rs[r] = rsqrtf(var + 1e-5f);
  }
#pragma unroll
  for (int nt = 0; nt < 2; ++nt) {
    const int c = wn * 32 + nt * 16 + l15;
    const float gg = gamma[c];
    const float bt = beta[c];
#pragma unroll
    for (int r = 0; r < 4; ++r) {
      const int row = m0 + 4 * g + r;
      out[(size_t)row * E + c] = (yv[nt][r] - mu[r]) * rs[r] * gg + bt;
    }
  }
}

}  // namespace

extern "C" void kernel_launch(void* const* d_in, const int* in_sizes, int n_in,
                              void* d_out, int out_size, void* d_ws, size_t ws_size,
                              hipStream_t stream) {
  const float* x     = (const float*)d_in[0];
  const float* pe    = (const float*)d_in[1];
  const int*   xb    = (const int*)d_in[2];
  const float* Wq    = (const float*)d_in[3];
  const float* Wk    = (const float*)d_in[4];
  const float* Wv    = (const float*)d_in[5];
  const float* bq    = (const float*)d_in[6];
  const float* bk    = (const float*)d_in[7];
  const float* bv    = (const float*)d_in[8];
  const float* Wo    = (const float*)d_in[9];
  const float* bo    = (const float*)d_in[10];
  const float* gamma = (const float*)d_in[11];
  const float* beta  = (const float*)d_in[12];
  float* out = (float*)d_out;

  char* wsb = (char*)d_ws;
  const size_t NE = (size_t)N * E;
  __bf16* qb16  = (__bf16*)(wsb);                  // 2 MB
  __bf16* kb16  = (__bf16*)(wsb + 2 * NE);         // 2 MB
  __bf16* vt16  = (__bf16*)(wsb + 4 * NE);         // 2 MB  [E][N]
  __bf16* ctx16 = (__bf16*)(wsb + 6 * NE);         // 2 MB
  int*    seg   = (int*)(wsb + 8 * NE);

  qkv_mfma<<<dim3(128, 3), 512, 0, stream>>>(x, pe, xb, Wq, Wk, Wv,
                                             bq, bk, bv, qb16, kb16, vt16, seg);
  attn_kernel<<<dim3(64, 8), 256, 0, stream>>>(qb16, kb16, vt16, xb, seg, ctx16);
  proj_ln<<<dim3(256), 512, 0, stream>>>(ctx16, x, Wo, bo, gamma, beta, out);
}

// Round 5
// 61.495 us; speedup vs baseline: 1.4541x; 1.3649x over previous
//
#include <hip/hip_runtime.h>
#include <math.h>

namespace {

constexpr int N  = 4096;
constexpr int E  = 256;
constexpr int H  = 8;
constexpr int DH = 32;
constexpr int BS = 8;
// fold 1/sqrt(DH) and log2(e): softmax in exp2 domain, no max subtraction
// (f32-safe: |s*CL| realistic max ~16, overflow at 127 -> 27 sigma margin)
constexpr float CL = 0.17677669529663687f * 1.4426950408889634f;

typedef __bf16 bf16x8 __attribute__((ext_vector_type(8)));
typedef __bf16 bf16x4 __attribute__((ext_vector_type(4)));
typedef float  f32x4  __attribute__((ext_vector_type(4)));

#if __has_builtin(__builtin_amdgcn_exp2f)
#define EXP2F(x) __builtin_amdgcn_exp2f(x)
#else
#define EXP2F(x) __expf((x) * 0.6931471805599453f)
#endif

__device__ inline bf16x8 pack8(float4 a, float4 b) {
  bf16x8 r;
  r[0] = (__bf16)a.x; r[1] = (__bf16)a.y; r[2] = (__bf16)a.z; r[3] = (__bf16)a.w;
  r[4] = (__bf16)b.x; r[5] = (__bf16)b.y; r[6] = (__bf16)b.z; r[7] = (__bf16)b.w;
  return r;
}

// ---------------------------------------------------------------------------
// prep: one memory-bound pass producing all bf16 operands.
//  blocks [0,512):   xpe = bf16(x+pe), xv = bf16(x)   (8 elems/thread)
//  blocks [512,640): wb[mat][n][k] = bf16(W)  mat: 0=Wq 1=Wk 2=Wv 3=Wo
//  block 640:        seg[t] via binary search on sorted xb
// Amortizes the f32->bf16 conversions that rounds 3-4 redid per GEMM block.
// ---------------------------------------------------------------------------
__global__ __launch_bounds__(256) void prep_kernel(
    const float* __restrict__ x, const float* __restrict__ pe,
    const int* __restrict__ xb,
    const float* __restrict__ Wq, const float* __restrict__ Wk,
    const float* __restrict__ Wv, const float* __restrict__ Wo,
    __bf16* __restrict__ xpe, __bf16* __restrict__ xv,
    __bf16* __restrict__ wb, int* __restrict__ seg)
{
  const int bid = blockIdx.x;
  if (bid < 512) {
    const size_t e0 = ((size_t)bid * 256 + threadIdx.x) * 8;
    float4 a0 = *(const float4*)(x + e0);
    float4 a1 = *(const float4*)(x + e0 + 4);
    const float4 p0 = *(const float4*)(pe + e0);
    const float4 p1 = *(const float4*)(pe + e0 + 4);
    *reinterpret_cast<bf16x8*>(xv + e0) = pack8(a0, a1);
    a0.x += p0.x; a0.y += p0.y; a0.z += p0.z; a0.w += p0.w;
    a1.x += p1.x; a1.y += p1.y; a1.z += p1.z; a1.w += p1.w;
    *reinterpret_cast<bf16x8*>(xpe + e0) = pack8(a0, a1);
  } else if (bid < 640) {
    const size_t e0 = ((size_t)(bid - 512) * 256 + threadIdx.x) * 8;
    const int mat = (int)(e0 >> 16);
    const size_t off = e0 & 65535;
    const float* __restrict__ W =
        (mat == 0) ? Wq : (mat == 1) ? Wk : (mat == 2) ? Wv : Wo;
    *reinterpret_cast<bf16x8*>(wb + e0) =
        pack8(*(const float4*)(W + off), *(const float4*)(W + off + 4));
  } else {
    if (threadIdx.x <= BS) {
      const int t = threadIdx.x;
      int lo = 0, hi = N;
      while (lo < hi) { int mid = (lo + hi) >> 1; if (xb[mid] < t) lo = mid + 1; else hi = mid; }
      seg[t] = lo;
    }
  }
}

// ---------------------------------------------------------------------------
// MFMA QKV, pure bf16 operands: out = A @ W^T + b.
// A = xpe (Q,K) or xv (V). 16-row blocks, 4 waves (wave = 64-col slice),
// grid (256, 3) = 768 blocks -> ~3 blocks/CU. K fully unrolled: all 8
// A-fragments hoisted, 32 independent 16B B-loads pipeline under the MFMAs.
// Q,K stored bf16 [N][E]; V stored transposed vt[E][N].
// ---------------------------------------------------------------------------
__global__ __launch_bounds__(256) void qkv_mfma(
    const __bf16* __restrict__ xpe, const __bf16* __restrict__ xv,
    const __bf16* __restrict__ wb,
    const float* __restrict__ bq, const float* __restrict__ bk,
    const float* __restrict__ bv,
    __bf16* __restrict__ qo, __bf16* __restrict__ ko,
    __bf16* __restrict__ vt)
{
  const int mat  = blockIdx.y;
  const int m0   = blockIdx.x * 16;
  const int wn   = threadIdx.x >> 6;
  const int lane = threadIdx.x & 63;
  const int l15  = lane & 15, g = lane >> 4;

  const __bf16* __restrict__ A = (mat < 2) ? xpe : xv;
  const __bf16* __restrict__ W = wb + (size_t)mat * E * E;
  const int mrow = m0 + l15;

  bf16x8 af[8];
#pragma unroll
  for (int kk = 0; kk < 8; ++kk)
    af[kk] = *reinterpret_cast<const bf16x8*>(A + (size_t)mrow * E + kk * 32 + 8 * g);

  f32x4 acc[4];
#pragma unroll
  for (int nt = 0; nt < 4; ++nt) acc[nt] = f32x4{0.f, 0.f, 0.f, 0.f};

#pragma unroll
  for (int kk = 0; kk < 8; ++kk) {
#pragma unroll
    for (int nt = 0; nt < 4; ++nt) {
      const bf16x8 wf = *reinterpret_cast<const bf16x8*>(
          W + (size_t)(wn * 64 + nt * 16 + l15) * E + kk * 32 + 8 * g);
      acc[nt] = __builtin_amdgcn_mfma_f32_16x16x32_bf16(wf, af[kk], acc[nt], 0, 0, 0);
    }
  }

  if (mat < 2) {
    __bf16* __restrict__ outb = mat ? ko : qo;
    const float* __restrict__ bi = mat ? bk : bq;
#pragma unroll
    for (int nt = 0; nt < 4; ++nt) {
      const int n_base = wn * 64 + nt * 16 + 4 * g;
      const float4 bb = *(const float4*)(bi + n_base);
      bf16x4 o;
      o.x = (__bf16)(acc[nt][0] + bb.x);
      o.y = (__bf16)(acc[nt][1] + bb.y);
      o.z = (__bf16)(acc[nt][2] + bb.z);
      o.w = (__bf16)(acc[nt][3] + bb.w);
      *reinterpret_cast<bf16x4*>(outb + (size_t)mrow * E + n_base) = o;
    }
  } else {
#pragma unroll
    for (int nt = 0; nt < 4; ++nt) {
      const int n_base = wn * 64 + nt * 16 + 4 * g;
      const float4 bb = *(const float4*)(bv + n_base);
      const float bbr[4] = {bb.x, bb.y, bb.z, bb.w};
#pragma unroll
      for (int r = 0; r < 4; ++r)
        vt[(size_t)(n_base + r) * N + mrow] = (__bf16)(acc[nt][r] + bbr[r]);
    }
  }
}

// ---------------------------------------------------------------------------
// MFMA flash attention, block-diagonal mask. No LDS, no barriers, zero
// per-tile cross-lane ops (unchanged from round 4):
//  - permuted key IDs make S^T accumulator regs land in P A-fragment slots
//  - fixed-base exp2 softmax (no running max; f32-safe by range)
// ---------------------------------------------------------------------------
__global__ __launch_bounds__(256) void attn_kernel(
    const __bf16* __restrict__ qb, const __bf16* __restrict__ kb,
    const __bf16* __restrict__ vt, const int* __restrict__ xb,
    const int* __restrict__ seg, __bf16* __restrict__ ctxb)
{
  const int h    = blockIdx.y;
  const int wv   = threadIdx.x >> 6;
  const int lane = threadIdx.x & 63;
  const int l15  = lane & 15;
  const int g    = lane >> 4;
  const int hd   = h * DH;
  const int rowbase = blockIdx.x * 64 + wv * 16;
  const int qrow = rowbase + l15;

  const int b  = xb[qrow];
  const int lo = seg[b];
  const int hi = seg[b + 1];

  const bf16x8 qf = *reinterpret_cast<const bf16x8*>(
      qb + (size_t)qrow * E + hd + g * 8);

  const int kstart = __shfl(lo, 0, 64);
  const int kend   = __shfl(hi, 15, 64);

  const int base_l = ((l15 & 12) << 1) + (l15 & 3);  // 8*(l15>>2) + (l15&3)

  f32x4 acc0 = {0.f, 0.f, 0.f, 0.f};
  f32x4 acc1 = {0.f, 0.f, 0.f, 0.f};
  float lsum = 0.f;

  for (int j0 = kstart & ~63; j0 < kend; j0 += 64) {
    bf16x8 kf[4];
#pragma unroll
    for (int mt = 0; mt < 4; ++mt) {
      const int krow = j0 + base_l + 32 * (mt >> 1) + 4 * (mt & 1);
      kf[mt] = *reinterpret_cast<const bf16x8*>(kb + (size_t)krow * E + hd + g * 8);
    }
    bf16x8 vf[2][2];
#pragma unroll
    for (int ks = 0; ks < 2; ++ks)
#pragma unroll
      for (int dh = 0; dh < 2; ++dh)
        vf[ks][dh] = *reinterpret_cast<const bf16x8*>(
            vt + (size_t)(hd + 16 * dh + l15) * N + j0 + 32 * ks + 8 * g);

    f32x4 s[4];
#pragma unroll
    for (int mt = 0; mt < 4; ++mt) {
      const f32x4 z = {0.f, 0.f, 0.f, 0.f};
      s[mt] = __builtin_amdgcn_mfma_f32_16x16x32_bf16(kf[mt], qf, z, 0, 0, 0);
    }

    bf16x8 pa[2];
#pragma unroll
    for (int ks = 0; ks < 2; ++ks)
#pragma unroll
      for (int b_ = 0; b_ < 2; ++b_)
#pragma unroll
        for (int r = 0; r < 4; ++r) {
          const int key = j0 + 32 * ks + 8 * g + 4 * b_ + r;
          const float sc = s[2 * ks + b_][r] * CL;
          const float e  = (key >= lo && key < hi) ? EXP2F(sc) : 0.f;
          lsum += e;
          pa[ks][4 * b_ + r] = (__bf16)e;
        }

#pragma unroll
    for (int ks = 0; ks < 2; ++ks) {
      acc0 = __builtin_amdgcn_mfma_f32_16x16x32_bf16(pa[ks], vf[ks][0], acc0, 0, 0, 0);
      acc1 = __builtin_amdgcn_mfma_f32_16x16x32_bf16(pa[ks], vf[ks][1], acc1, 0, 0, 0);
    }
  }

  lsum += __shfl_xor(lsum, 16, 64);
  lsum += __shfl_xor(lsum, 32, 64);
  const float inv = 1.0f / lsum;
  float invr[4];
#pragma unroll
  for (int r = 0; r < 4; ++r) invr[r] = __shfl(inv, 4 * g + r, 64);

  __bf16* __restrict__ cb = ctxb + (size_t)rowbase * E + hd + l15;
#pragma unroll
  for (int r = 0; r < 4; ++r) {
    cb[(size_t)(4 * g + r) * E]      = (__bf16)(acc0[r] * invr[r]);
    cb[(size_t)(4 * g + r) * E + 16] = (__bf16)(acc1[r] * invr[r]);
  }
}

// ---------------------------------------------------------------------------
// MFMA output projection + residual + LayerNorm, fused. Wo from prepped bf16.
// 16-row blocks, grid 256, 8 waves (wave = 32-col slice). K fully unrolled.
// Orientation: D = mfma(ctx_frag, Wo_frag) -> row = 4g+r (query), col = l15
// so LN output stores are row-contiguous.
// ---------------------------------------------------------------------------
__global__ __launch_bounds__(512) void proj_ln(
    const __bf16* __restrict__ ctx, const float* __restrict__ x,
    const __bf16* __restrict__ wo, const float* __restrict__ bo,
    const float* __restrict__ gamma, const float* __restrict__ beta,
    float* __restrict__ out)
{
  const int m0   = blockIdx.x * 16;
  const int wn   = threadIdx.x >> 6;
  const int lane = threadIdx.x & 63;
  const int l15  = lane & 15, g = lane >> 4;

  bf16x8 af[8];
#pragma unroll
  for (int kk = 0; kk < 8; ++kk)
    af[kk] = *reinterpret_cast<const bf16x8*>(
        ctx + (size_t)(m0 + l15) * E + kk * 32 + 8 * g);

  f32x4 acc[2];
  acc[0] = f32x4{0.f, 0.f, 0.f, 0.f};
  acc[1] = f32x4{0.f, 0.f, 0.f, 0.f};

#pragma unroll
  for (int kk = 0; kk < 8; ++kk) {
#pragma unroll
    for (int nt = 0; nt < 2; ++nt) {
      const bf16x8 wf = *reinterpret_cast<const bf16x8*>(
          wo + (size_t)(wn * 32 + nt * 16 + l15) * E + kk * 32 + 8 * g);
      acc[nt] = __builtin_amdgcn_mfma_f32_16x16x32_bf16(af[kk], wf, acc[nt], 0, 0, 0);
    }
  }

  float yv[2][4];
  float s1[4], s2[4];
#pragma unroll
  for (int r = 0; r < 4; ++r) { s1[r] = 0.f; s2[r] = 0.f; }
#pragma unroll
  for (int nt = 0; nt < 2; ++nt) {
    const int c = wn * 32 + nt * 16 + l15;
    const float bb = bo[c];
#pragma unroll
    for (int r = 0; r < 4; ++r) {
      const int row = m0 + 4 * g + r;
      const float y = acc[nt][r] + bb + x[(size_t)row * E + c];
      yv[nt][r] = y;
      s1[r] += y;
      s2[r] += y * y;
    }
  }
#pragma unroll
  for (int off = 1; off < 16; off <<= 1) {
#pragma unroll
    for (int r = 0; r < 4; ++r) {
      s1[r] += __shfl_xor(s1[r], off, 64);
      s2[r] += __shfl_xor(s2[r], off, 64);
    }
  }
  __shared__ float redS[8][16];
  __shared__ float redQ[8][16];
  if (l15 == 0) {
#pragma unroll
    for (int r = 0; r < 4; ++r) {
      redS[wn][4 * g + r] = s1[r];
      redQ[wn][4 * g + r] = s2[r];
    }
  }
  __syncthreads();
  float mu[4], rs[4];
#pragma unroll
  for (int r = 0; r < 4; ++r) {
    float ts = 0.f, tq = 0.f;
#pragma unroll
    for (int w = 0; w < 8; ++w) { ts += redS[w][4 * g + r]; tq += redQ[w][4 * g + r]; }
    mu[r] = ts * (1.0f / E);
    const float var = tq * (1.0f / E) - mu[r] * mu[r];
    rs[r] = rsqrtf(var + 1e-5f);
  }
#pragma unroll
  for (int nt = 0; nt < 2; ++nt) {
    const int c = wn * 32 + nt * 16 + l15;
    const float gg = gamma[c];
    const float bt = beta[c];
#pragma unroll
    for (int r = 0; r < 4; ++r) {
      const int row = m0 + 4 * g + r;
      out[(size_t)row * E + c] = (yv[nt][r] - mu[r]) * rs[r] * gg + bt;
    }
  }
}

}  // namespace

extern "C" void kernel_launch(void* const* d_in, const int* in_sizes, int n_in,
                              void* d_out, int out_size, void* d_ws, size_t ws_size,
                              hipStream_t stream) {
  const float* x     = (const float*)d_in[0];
  const float* pe    = (const float*)d_in[1];
  const int*   xb    = (const int*)d_in[2];
  const float* Wq    = (const float*)d_in[3];
  const float* Wk    = (const float*)d_in[4];
  const float* Wv    = (const float*)d_in[5];
  const float* bq    = (const float*)d_in[6];
  const float* bk    = (const float*)d_in[7];
  const float* bv    = (const float*)d_in[8];
  const float* Wo    = (const float*)d_in[9];
  const float* bo    = (const float*)d_in[10];
  const float* gamma = (const float*)d_in[11];
  const float* beta  = (const float*)d_in[12];
  float* out = (float*)d_out;

  char* wsb = (char*)d_ws;
  const size_t NE = (size_t)N * E;          // 1,048,576 elements
  __bf16* qb16  = (__bf16*)(wsb);                   // 2 MB
  __bf16* kb16  = (__bf16*)(wsb + 2 * NE);          // 2 MB
  __bf16* vt16  = (__bf16*)(wsb + 4 * NE);          // 2 MB  [E][N]
  __bf16* ctx16 = (__bf16*)(wsb + 6 * NE);          // 2 MB
  __bf16* xpe16 = (__bf16*)(wsb + 8 * NE);          // 2 MB
  __bf16* xv16  = (__bf16*)(wsb + 10 * NE);         // 2 MB
  __bf16* wb16  = (__bf16*)(wsb + 12 * NE);         // 512 KB (4 mats)
  int*    seg   = (int*)(wsb + 12 * NE + 4 * (size_t)E * E * 2);

  prep_kernel<<<dim3(641), 256, 0, stream>>>(x, pe, xb, Wq, Wk, Wv, Wo,
                                             xpe16, xv16, wb16, seg);
  qkv_mfma<<<dim3(256, 3), 256, 0, stream>>>(xpe16, xv16, wb16, bq, bk, bv,
                                             qb16, kb16, vt16);
  attn_kernel<<<dim3(64, 8), 256, 0, stream>>>(qb16, kb16, vt16, xb, seg, ctx16);
  proj_ln<<<dim3(256), 512, 0, stream>>>(ctx16, x, wb16 + 3 * (size_t)E * E,
                                         bo, gamma, beta, out);
}